// Round 5
// baseline (509.380 us; speedup 1.0000x reference)
//
#include <hip/hip_runtime.h>
#include <hip/hip_bf16.h>
#include <cstdint>
#include <cstddef>

// MHA forward. b=4, n=2048, d_model=1024, heads=16, dk=64, causal.
// Inputs: float32 (confirmed R1-R5). Output: float32 (confirmed R5 green).
// Compute: bf16 MFMA, fp32 accumulate; intermediates bf16 row-major [b*n,1024].
//
// R11: R10's gate proved ws_size < 34 MB+16 (fallback ran @499) => R9 died of
// ws overflow. This round fits the global_load_lds GEMM plan in EXACTLY the
// proven footprint (ws = 16 B + qws 16 MB + kws 16 MB; d_out = vws lo 16 MB +
// abuf hi 16 MB) by recycling regions in dependency order:
//   V first : wslot = kws region (not yet live). gemm_lds2(abuf, wslot)->vws
//   Q second: wslot = kws region (still free).   gemm_lds2(abuf, wslot)->qws
//   K third : no region free -> gemm_hyb: A bf16 via global_load_lds,
//             W f32 reg-staged+cvt (half the old staging work). -> kws
//   flash   : unchanged (R7 structure, 207 us)
//   O last  : K dead -> wslot = kws region. gemm_lds2(qws, wslot)->d_out f32
// Both new GEMMs: double-buffered LDS, ONE barrier per k-step, prefetch of
// tile t+1 issued right after sync(t) (g2l latency hides under compute(t),
// drained by sync(t+1)). Same RNE bf16 casts as R2 -> bit-identical results.

typedef __bf16 bf16_t;
typedef bf16_t bf16x8 __attribute__((ext_vector_type(8)));
typedef float floatx4 __attribute__((ext_vector_type(4)));

#define MFMA(a, b, c) __builtin_amdgcn_mfma_f32_16x16x32_bf16((a), (b), (c), 0, 0, 0)
#define NEG_BIG (-30000.0f)  // exp2-domain sentinel; v_exp_f32 underflows to 0

static __device__ __forceinline__ bf16_t f2bf(float x) { return (bf16_t)x; }

static __device__ __forceinline__ bf16x8 cvt8p(const floatx4 a, const floatx4 b) {
  bf16x8 r;
  r[0] = (bf16_t)a[0]; r[1] = (bf16_t)a[1]; r[2] = (bf16_t)a[2]; r[3] = (bf16_t)a[3];
  r[4] = (bf16_t)b[0]; r[5] = (bf16_t)b[1]; r[6] = (bf16_t)b[2]; r[7] = (bf16_t)b[3];
  return r;
}

// global -> LDS direct copy, 16 B/lane. dest = wave-uniform base + lane*16.
static __device__ __forceinline__ void g2l16(const void* g, void* l) {
  __builtin_amdgcn_global_load_lds(
      (const __attribute__((address_space(1))) void*)g,
      (__attribute__((address_space(3))) void*)l, 16, 0, 0);
}

// f32-vs-bf16 sniffer on w_q's first 64 uint16s (validated: picks f32 path).
__global__ void detect_dtype(const unsigned short* __restrict__ w,
                             int* __restrict__ flag) {
  const unsigned short u = w[threadIdx.x];
  const bool big = (u & 0x7F80u) >= 0x3F80u;
  const unsigned long long m = __ballot(big);
  if (threadIdx.x == 0) *flag = (m != 0ull) ? 1 : 0;
}

// ---------------------------------------------------------------------------
// dst[bf16] = cvt(src) — src is f32 (flag) or bf16 (copy). n8 = elems/8.
// ---------------------------------------------------------------------------
__global__ __launch_bounds__(256)
void cvt_bf16(const void* __restrict__ src, bf16_t* __restrict__ dst,
              int n8, const int* __restrict__ flag)
{
  const int i = blockIdx.x * 256 + threadIdx.x;
  if (i >= n8) return;
  if (*flag) {
    const floatx4* s = (const floatx4*)src;
    ((bf16x8*)dst)[i] = cvt8p(s[2 * i], s[2 * i + 1]);
  } else {
    ((bf16x8*)dst)[i] = ((const bf16x8*)src)[i];
  }
}

// ---------------------------------------------------------------------------
// gemm_lds2: C[M,1024] = A @ W^T, all-bf16 in, OutT out. m97 structure +
// double-buffer: tile 128x128, BK=32, 4 waves (2x2), 4x4 mfma_16x16x32/wave.
// Per k-step each wave issues 2+2 global_load_lds_dwordx4 into linear
// [128][32] LDS (chunk = 16 rows; lane -> row ch*16+lane/4, col (lane&3)*8;
// HW writes base+lane*16). ONE barrier per k-step: sync(t) drains g2l(t)
// (issued after sync(t-1), hidden under compute(t-1)).
// ---------------------------------------------------------------------------
template <typename OutT>
__global__ __launch_bounds__(256, 2)
void gemm_lds2(const bf16_t* __restrict__ A, const bf16_t* __restrict__ W,
               OutT* __restrict__ C)
{
  const int K = 1024;
  __shared__ __align__(16) bf16_t sA[2][128 * 32];  // 2 x 8 KB
  __shared__ __align__(16) bf16_t sB[2][128 * 32];  // 2 x 8 KB
  const int tid  = threadIdx.x;
  const int wave = tid >> 6;
  const int lane = tid & 63;
  const int wm = wave >> 1, wn = wave & 1;
  const int bm = blockIdx.y * 128, bn = blockIdx.x * 128;
  const int quad = lane >> 4, r16 = lane & 15;

  floatx4 acc[4][4];
  #pragma unroll
  for (int i = 0; i < 4; ++i)
    #pragma unroll
    for (int j = 0; j < 4; ++j) acc[i][j] = {0.f, 0.f, 0.f, 0.f};

  // staging geometry (chunk = wave*2 + c, c in {0,1}; 512 elems = 1 KB each)
  const int ch0 = wave * 2;
  const int r0  = lane >> 2;        // 0..15 within chunk
  const int ce  = (lane & 3) * 8;   // col element 0,8,16,24
  const bf16_t* Ag0 = A + (size_t)(bm + ch0 * 16 + r0) * K + ce;
  const bf16_t* Ag1 = Ag0 + (size_t)16 * K;
  const bf16_t* Wg0 = W + (size_t)(bn + ch0 * 16 + r0) * K + ce;
  const bf16_t* Wg1 = Wg0 + (size_t)16 * K;

  auto stage = [&](int k0, int b) {
    g2l16(Ag0 + k0, &sA[b][ch0 * 512]);
    g2l16(Ag1 + k0, &sA[b][(ch0 + 1) * 512]);
    g2l16(Wg0 + k0, &sB[b][ch0 * 512]);
    g2l16(Wg1 + k0, &sB[b][(ch0 + 1) * 512]);
  };

  stage(0, 0);
  for (int t = 0; t < 32; ++t) {
    const int buf = t & 1;
    __syncthreads();                       // drains g2l(t): tiles resident
    if (t + 1 < 32) stage((t + 1) * 32, buf ^ 1);  // hides under compute(t)

    bf16x8 af[4], bv[4];
    #pragma unroll
    for (int mi = 0; mi < 4; ++mi)
      af[mi] = *(const bf16x8*)&sA[buf][(wm * 64 + mi * 16 + r16) * 32 + quad * 8];
    #pragma unroll
    for (int ni = 0; ni < 4; ++ni)
      bv[ni] = *(const bf16x8*)&sB[buf][(wn * 64 + ni * 16 + r16) * 32 + quad * 8];
    #pragma unroll
    for (int mi = 0; mi < 4; ++mi)
      #pragma unroll
      for (int ni = 0; ni < 4; ++ni)
        acc[mi][ni] = MFMA(af[mi], bv[ni], acc[mi][ni]);
  }

  #pragma unroll
  for (int mi = 0; mi < 4; ++mi)
    #pragma unroll
    for (int ni = 0; ni < 4; ++ni)
      #pragma unroll
      for (int r = 0; r < 4; ++r) {
        const int row = bm + wm * 64 + mi * 16 + quad * 4 + r;
        const int col = bn + wn * 64 + ni * 16 + r16;
        C[(size_t)row * 1024 + col] = (OutT)acc[mi][ni][r];
      }
}

// ---------------------------------------------------------------------------
// gemm_hyb: A bf16 via global_load_lds (linear [128][32]); W external f32 (or
// bf16 per flag) reg-staged + cvt into padded [128][40] LDS. Double-buffered,
// one barrier per k-step. Used for the K projection (no W-slot available).
// ---------------------------------------------------------------------------
template <bool WF32>
static __device__ __forceinline__
void gemm_hyb_core(const bf16_t* __restrict__ A, const void* __restrict__ Wv,
                   bf16_t* __restrict__ C,
                   bf16_t (*sA)[128 * 32], bf16_t (*sB)[128 * 40])
{
  const int K = 1024;
  const int tid  = threadIdx.x;
  const int wave = tid >> 6;
  const int lane = tid & 63;
  const int wm = wave >> 1, wn = wave & 1;
  const int bm = blockIdx.y * 128, bn = blockIdx.x * 128;
  const int quad = lane >> 4, r16 = lane & 15;

  floatx4 acc[4][4];
  #pragma unroll
  for (int i = 0; i < 4; ++i)
    #pragma unroll
    for (int j = 0; j < 4; ++j) acc[i][j] = {0.f, 0.f, 0.f, 0.f};

  // A-side g2l geometry
  const int ch0 = wave * 2;
  const int r0  = lane >> 2;
  const int ce  = (lane & 3) * 8;
  const bf16_t* Ag0 = A + (size_t)(bm + ch0 * 16 + r0) * K + ce;
  const bf16_t* Ag1 = Ag0 + (size_t)16 * K;

  // W-side reg-stage geometry (each thread: rows srow, srow+64; 8 elems)
  const int srow = tid >> 2;
  const int scol = (tid & 3) * 8;
  const size_t w0 = (size_t)(bn + srow) * K + scol;
  const size_t w1 = w0 + (size_t)64 * K;

  floatx4 fw[2][2];
  bf16x8  bw[2];
  auto stageW = [&](int k0) {
    if constexpr (WF32) {
      const float* Wf = (const float*)Wv;
      fw[0][0] = *(const floatx4*)(Wf + w0 + k0);
      fw[0][1] = *(const floatx4*)(Wf + w0 + k0 + 4);
      fw[1][0] = *(const floatx4*)(Wf + w1 + k0);
      fw[1][1] = *(const floatx4*)(Wf + w1 + k0 + 4);
    } else {
      const bf16_t* Wb = (const bf16_t*)Wv;
      bw[0] = *(const bf16x8*)(Wb + w0 + k0);
      bw[1] = *(const bf16x8*)(Wb + w1 + k0);
    }
  };

  stageW(0);
  g2l16(Ag0, &sA[0][ch0 * 512]);
  g2l16(Ag1, &sA[0][(ch0 + 1) * 512]);

  for (int t = 0; t < 32; ++t) {
    const int buf = t & 1;
    // write W(t) regs -> sB[buf] (last read of sB[buf] was compute(t-2),
    // ordered behind sync(t-1) which every wave has passed)
    {
      bf16x8 vb0, vb1;
      if constexpr (WF32) { vb0 = cvt8p(fw[0][0], fw[0][1]); vb1 = cvt8p(fw[1][0], fw[1][1]); }
      else                { vb0 = bw[0]; vb1 = bw[1]; }
      *(bf16x8*)&sB[buf][srow * 40 + scol]        = vb0;
      *(bf16x8*)&sB[buf][(srow + 64) * 40 + scol] = vb1;
    }
    __syncthreads();  // drains g2l A(t); W writes visible
    if (t + 1 < 32) {
      const int k0 = (t + 1) * 32;
      g2l16(Ag0 + k0, &sA[buf ^ 1][ch0 * 512]);
      g2l16(Ag1 + k0, &sA[buf ^ 1][(ch0 + 1) * 512]);
      stageW(k0);
    }

    bf16x8 af[4], bv[4];
    #pragma unroll
    for (int mi = 0; mi < 4; ++mi)
      af[mi] = *(const bf16x8*)&sA[buf][(wm * 64 + mi * 16 + r16) * 32 + quad * 8];
    #pragma unroll
    for (int ni = 0; ni < 4; ++ni)
      bv[ni] = *(const bf16x8*)&sB[buf][(wn * 64 + ni * 16 + r16) * 40 + quad * 8];
    #pragma unroll
    for (int mi = 0; mi < 4; ++mi)
      #pragma unroll
      for (int ni = 0; ni < 4; ++ni)
        acc[mi][ni] = MFMA(af[mi], bv[ni], acc[mi][ni]);
  }

  #pragma unroll
  for (int mi = 0; mi < 4; ++mi)
    #pragma unroll
    for (int ni = 0; ni < 4; ++ni)
      #pragma unroll
      for (int r = 0; r < 4; ++r) {
        const int row = bm + wm * 64 + mi * 16 + quad * 4 + r;
        const int col = bn + wn * 64 + ni * 16 + r16;
        C[(size_t)row * 1024 + col] = (bf16_t)acc[mi][ni][r];
      }
}

__global__ __launch_bounds__(256, 2)
void gemm_hyb(const bf16_t* __restrict__ A, const void* __restrict__ Wv,
              bf16_t* __restrict__ C, const int* __restrict__ flag)
{
  __shared__ __align__(16) bf16_t sA[2][128 * 32];  // 16 KB
  __shared__ __align__(16) bf16_t sB[2][128 * 40];  // 20 KB
  if (*flag) gemm_hyb_core<true >(A, Wv, C, sA, sB);
  else       gemm_hyb_core<false>(A, Wv, C, sA, sB);
}

// ---------------------------------------------------------------------------
// Causal MFMA flash attention over row-major [8192][1024] bf16 q/k/v, head =
// 64-col slice. Block = 256 threads (4 waves): one (bh, 64-row q-tile).
// Wave w owns S/O rows [w*16, w*16+16). BKV = 64. Finite mask sentinels.
// All LDS tiles [64][64] XOR-swizzled: idx = row*64 + (col ^ ((row&7)<<3)),
// applied identically on write and read -> ds_read_b128 conflict-free.
// Next K/V tile prefetched into regs after the stage barrier (T14).
// Output in-place over q rows (block-private).        [R7: 305 -> 217 us]
// ---------------------------------------------------------------------------
__global__ __launch_bounds__(256, 4)
void flash_attn(bf16_t* qio, const bf16_t* __restrict__ kh,
                const bf16_t* __restrict__ vh)
{
  __shared__ __align__(16) bf16_t sK[64 * 64];    // [kv][d]  8 KB, swizzled
  __shared__ __align__(16) bf16_t sVt[64 * 64];   // [d][kv]  8 KB, swizzled
  __shared__ __align__(16) bf16_t sP[64 * 64];    // [q][kv]  8 KB, swizzled
  const int tid  = threadIdx.x;
  const int wave = tid >> 6;
  const int lane = tid & 63;
  const int quad = lane >> 4, r16 = lane & 15;
  const int b = blockIdx.x >> 4, h = blockIdx.x & 15;
  const int q0 = (int)(gridDim.y - 1 - blockIdx.y) * 64;  // heavy tiles first
  const size_t hb = ((size_t)b * 2048) * 1024 + (size_t)h * 64;
  const int swl = (r16 & 7) << 3;  // read-side XOR for r16-indexed rows

  bf16x8 qf[2];
  #pragma unroll
  for (int ks = 0; ks < 2; ++ks)
    qf[ks] = *(const bf16x8*)(qio + hb +
        (size_t)(q0 + wave * 16 + r16) * 1024 + ks * 32 + quad * 8);

  floatx4 o[4];
  float mrow[4], lrow[4];
  #pragma unroll
  for (int nd = 0; nd < 4; ++nd) o[nd] = {0.f, 0.f, 0.f, 0.f};
  #pragma unroll
  for (int r = 0; r < 4; ++r) { mrow[r] = NEG_BIG; lrow[r] = 0.f; }

  const float sc = 0.125f * 1.44269504089f;  // 1/sqrt(64) * log2(e)
  const int kend = q0 + 64;

  bf16x8 kst[2], vst[2];
  #pragma unroll
  for (int j = 0; j < 2; ++j) {
    const int c = j * 256 + tid;
    kst[j] = *(const bf16x8*)(kh + hb + (size_t)(c >> 3) * 1024 + (c & 7) * 8);
    vst[j] = *(const bf16x8*)(vh + hb + (size_t)(c & 63) * 1024 + (c >> 6) * 8);
  }

  for (int kv0 = 0; kv0 < kend; kv0 += 64) {
    #pragma unroll
    for (int j = 0; j < 2; ++j) {
      const int c = j * 256 + tid;
      const int krow = c >> 3, kcol = (c & 7) * 8;
      *(bf16x8*)&sK[krow * 64 + (kcol ^ ((krow & 7) << 3))] = kst[j];
      const int vkv = c & 63, vd = (c >> 6) * 8;
      #pragma unroll
      for (int e = 0; e < 8; ++e)        // row = vd+e, (row&7)==e since vd%8==0
        sVt[(vd + e) * 64 + (vkv ^ (e << 3))] = vst[j][e];
    }
    __syncthreads();

    if (kv0 + 64 < kend) {
      #pragma unroll
      for (int j = 0; j < 2; ++j) {
        const int c = j * 256 + tid;
        kst[j] = *(const bf16x8*)(kh + hb + (size_t)(kv0 + 64 + (c >> 3)) * 1024 + (c & 7) * 8);
        vst[j] = *(const bf16x8*)(vh + hb + (size_t)(kv0 + 64 + (c & 63)) * 1024 + (c >> 6) * 8);
      }
    }

    floatx4 s[4];
    #pragma unroll
    for (int nk = 0; nk < 4; ++nk) s[nk] = {0.f, 0.f, 0.f, 0.f};
    #pragma unroll
    for (int ks = 0; ks < 2; ++ks) {
      bf16x8 bk[4];
      #pragma unroll
      for (int nk = 0; nk < 4; ++nk)
        bk[nk] = *(const bf16x8*)&sK[(nk * 16 + r16) * 64 + ((ks * 32 + quad * 8) ^ swl)];
      #pragma unroll
      for (int nk = 0; nk < 4; ++nk)
        s[nk] = MFMA(qf[ks], bk[nk], s[nk]);
    }

    const int rowb = q0 + wave * 16 + quad * 4;
    const bool domask = (kv0 + 63 > rowb);
    #pragma unroll
    for (int nk = 0; nk < 4; ++nk) {
      const int col = kv0 + nk * 16 + r16;
      #pragma unroll
      for (int r = 0; r < 4; ++r) {
        float t = s[nk][r] * sc;
        if (domask && col > rowb + r) t = NEG_BIG;
        s[nk][r] = t;
      }
    }

    #pragma unroll
    for (int r = 0; r < 4; ++r) {
      float mx = fmaxf(fmaxf(s[0][r], s[1][r]), fmaxf(s[2][r], s[3][r]));
      #pragma unroll
      for (int off = 8; off >= 1; off >>= 1)
        mx = fmaxf(mx, __shfl_xor(mx, off, 64));
      const float mnew  = fmaxf(mrow[r], mx);
      const float alpha = exp2f(mrow[r] - mnew);
      mrow[r] = mnew;
      float ls = 0.f;
      const int prow = wave * 16 + quad * 4 + r;
      const int psw  = (prow & 7) << 3;
      #pragma unroll
      for (int nk = 0; nk < 4; ++nk) {
        const bf16_t pb = f2bf(exp2f(s[nk][r] - mnew));
        ls += (float)pb;  // denominator matches the bf16 P used in PV
        sP[prow * 64 + ((nk * 16 + r16) ^ psw)] = pb;
      }
      #pragma unroll
      for (int off = 8; off >= 1; off >>= 1)
        ls += __shfl_xor(ls, off, 64);
      lrow[r] = lrow[r] * alpha + ls;
      #pragma unroll
      for (int nd = 0; nd < 4; ++nd) o[nd][r] *= alpha;
    }
    __syncthreads();  // sP visible across lanes

    #pragma unroll
    for (int ks = 0; ks < 2; ++ks) {
      const int cb = (ks * 32 + quad * 8) ^ swl;
      const bf16x8 pa = *(const bf16x8*)&sP[(wave * 16 + r16) * 64 + cb];
      bf16x8 vb[4];
      #pragma unroll
      for (int nd = 0; nd < 4; ++nd)
        vb[nd] = *(const bf16x8*)&sVt[(nd * 16 + r16) * 64 + cb];
      #pragma unroll
      for (int nd = 0; nd < 4; ++nd)
        o[nd] = MFMA(pa, vb[nd], o[nd]);
    }
    __syncthreads();  // protect sK/sVt/sP for next iteration
  }

  #pragma unroll
  for (int r = 0; r < 4; ++r) {
    const float inv = 1.f / lrow[r];
    const int row = q0 + wave * 16 + quad * 4 + r;
    #pragma unroll
    for (int nd = 0; nd < 4; ++nd)
      qio[hb + (size_t)row * 1024 + nd * 16 + r16] = f2bf(o[nd][r] * inv);
  }
}

// ---------------------------------------------------------------------------
extern "C" void kernel_launch(void* const* d_in, const int* in_sizes, int n_in,
                              void* d_out, int out_size, void* d_ws, size_t ws_size,
                              hipStream_t stream) {
  (void)in_sizes; (void)n_in; (void)out_size; (void)ws_size;
  const size_t TSZ = (size_t)8192 * 1024;       // elems per [8192,1024] bf16
  const size_t WSZ = (size_t)1024 * 1024;       // elems per [1024,1024] bf16
  int*    flag = (int*)d_ws;
  bf16_t* qws  = (bf16_t*)((char*)d_ws + 16);   // ws lo  16 MB
  bf16_t* kws  = qws + TSZ;                     // ws hi  16 MB (also W-slot)
  bf16_t* vws  = (bf16_t*)d_out;                // d_out lo 16 MB (bf16 V)
  bf16_t* abuf = (bf16_t*)d_out + TSZ;          // d_out hi 16 MB (converted A)

  const int nA8 = (int)(TSZ / 8);
  const int nW8 = (int)(WSZ / 8);

  detect_dtype<<<1, 64, 0, stream>>>((const unsigned short*)d_in[3], flag);

  const dim3 gg(8, 64);  // (N/128, M/128)

  // V first: kws region free -> holds converted w_v
  cvt_bf16<<<nA8 / 256, 256, 0, stream>>>(d_in[2], abuf, nA8, flag);
  cvt_bf16<<<nW8 / 256, 256, 0, stream>>>(d_in[5], kws, nW8, flag);
  gemm_lds2<bf16_t><<<gg, 256, 0, stream>>>(abuf, kws, vws);

  // Q second: kws region still free -> holds converted w_q
  cvt_bf16<<<nA8 / 256, 256, 0, stream>>>(d_in[0], abuf, nA8, flag);
  cvt_bf16<<<nW8 / 256, 256, 0, stream>>>(d_in[3], kws, nW8, flag);
  gemm_lds2<bf16_t><<<gg, 256, 0, stream>>>(abuf, kws, qws);

  // K third: no free region -> hybrid (W f32 reg-staged from d_in)
  cvt_bf16<<<nA8 / 256, 256, 0, stream>>>(d_in[1], abuf, nA8, flag);
  gemm_hyb<<<gg, 256, 0, stream>>>(abuf, d_in[4], kws, flag);

  flash_attn<<<dim3(64, 32), 256, 0, stream>>>(qws, kws, vws);

  // Output projection: K dead -> kws region holds converted w_o
  cvt_bf16<<<nW8 / 256, 256, 0, stream>>>(d_in[6], kws, nW8, flag);
  gemm_lds2<float><<<gg, 256, 0, stream>>>(qws, kws, (float*)d_out);
}

// Round 6
// 420.167 us; speedup vs baseline: 1.2123x; 1.2123x over previous
//
#include <hip/hip_runtime.h>
#include <hip/hip_bf16.h>
#include <cstdint>
#include <cstddef>

// MHA forward. b=4, n=2048, d_model=1024, heads=16, dk=64, causal.
// Inputs: float32 (confirmed R1-R5). Output: float32 (confirmed R5 green).
// Compute: bf16 MFMA, fp32 accumulate; intermediates bf16 row-major [b*n,1024].
//
// R12: two targeted fixes from the R11 post-mortem (gemm_lds2 netted ~0):
//  1) XCD swizzle for GEMMs: natural dispatch gives XCD = bn -> each XCD
//     streams the whole 16 MB A through its 4 MB L2. Remap (bijective,
//     nwg=512): XCD j owns bm-panels [j*8, j*8+8) x all bn -> 2 MB A + 2 MB W
//     working set, L2-resident. Same for flash: all 32 q-tiles of one bh on
//     one XCD -> K/V (512 KB) L2-resident (FETCH was 105 MB vs 48 ideal).
//  2) flash softmax was the VALU bottleneck (VALUBusy 38% vs MfmaUtil 7%):
//     swapped QK^T (mfma(K,Q), same fragments, args swapped) puts a full
//     q-row in each lane: row-reduce = 15 local fmax + 2 shfl (was 32 shfl),
//     P-write = 4x8B stores (was 16 scalar), alpha broadcast 4 shfl only on
//     tiles where a row-max grows (T13 skip-rescale), mrow/lrow scalar.

typedef __bf16 bf16_t;
typedef bf16_t bf16x4 __attribute__((ext_vector_type(4)));
typedef bf16_t bf16x8 __attribute__((ext_vector_type(8)));
typedef float floatx4 __attribute__((ext_vector_type(4)));

#define MFMA(a, b, c) __builtin_amdgcn_mfma_f32_16x16x32_bf16((a), (b), (c), 0, 0, 0)
#define NEG_BIG (-30000.0f)  // exp2-domain sentinel; v_exp_f32 underflows to 0

static __device__ __forceinline__ bf16_t f2bf(float x) { return (bf16_t)x; }

static __device__ __forceinline__ bf16x8 cvt8p(const floatx4 a, const floatx4 b) {
  bf16x8 r;
  r[0] = (bf16_t)a[0]; r[1] = (bf16_t)a[1]; r[2] = (bf16_t)a[2]; r[3] = (bf16_t)a[3];
  r[4] = (bf16_t)b[0]; r[5] = (bf16_t)b[1]; r[6] = (bf16_t)b[2]; r[7] = (bf16_t)b[3];
  return r;
}

// global -> LDS direct copy, 16 B/lane. dest = wave-uniform base + lane*16.
static __device__ __forceinline__ void g2l16(const void* g, void* l) {
  __builtin_amdgcn_global_load_lds(
      (const __attribute__((address_space(1))) void*)g,
      (__attribute__((address_space(3))) void*)l, 16, 0, 0);
}

// f32-vs-bf16 sniffer on w_q's first 64 uint16s (validated: picks f32 path).
__global__ void detect_dtype(const unsigned short* __restrict__ w,
                             int* __restrict__ flag) {
  const unsigned short u = w[threadIdx.x];
  const bool big = (u & 0x7F80u) >= 0x3F80u;
  const unsigned long long m = __ballot(big);
  if (threadIdx.x == 0) *flag = (m != 0ull) ? 1 : 0;
}

// ---------------------------------------------------------------------------
// dst[bf16] = cvt(src) — src is f32 (flag) or bf16 (copy). n8 = elems/8.
// ---------------------------------------------------------------------------
__global__ __launch_bounds__(256)
void cvt_bf16(const void* __restrict__ src, bf16_t* __restrict__ dst,
              int n8, const int* __restrict__ flag)
{
  const int i = blockIdx.x * 256 + threadIdx.x;
  if (i >= n8) return;
  if (*flag) {
    const floatx4* s = (const floatx4*)src;
    ((bf16x8*)dst)[i] = cvt8p(s[2 * i], s[2 * i + 1]);
  } else {
    ((bf16x8*)dst)[i] = ((const bf16x8*)src)[i];
  }
}

// XCD remap for the 8x64 GEMM grid (nwg=512, %8==0 -> bijective):
// XCD j <- f%8 owns bm-panels [j*8, j*8+8) x all 8 bn. 2MB A + 2MB W per XCD.
static __device__ __forceinline__ void gemm_tile_map(int& bm, int& bn) {
  const int f  = (int)(blockIdx.y * gridDim.x + blockIdx.x);
  const int xj = f & 7, sq = f >> 3;
  bm = ((xj << 3) | (sq >> 3)) * 128;
  bn = (sq & 7) * 128;
}

// ---------------------------------------------------------------------------
// gemm_lds2: C[M,1024] = A @ W^T, all-bf16 in, OutT out. m97 structure +
// double-buffer: tile 128x128, BK=32, 4 waves (2x2), 4x4 mfma_16x16x32/wave.
// Per k-step each wave issues 2+2 global_load_lds_dwordx4 into linear
// [128][32] LDS. ONE barrier per k-step: sync(t) drains g2l(t) (issued after
// sync(t-1), hidden under compute(t-1)).
// ---------------------------------------------------------------------------
template <typename OutT>
__global__ __launch_bounds__(256, 2)
void gemm_lds2(const bf16_t* __restrict__ A, const bf16_t* __restrict__ W,
               OutT* __restrict__ C)
{
  const int K = 1024;
  __shared__ __align__(16) bf16_t sA[2][128 * 32];  // 2 x 8 KB
  __shared__ __align__(16) bf16_t sB[2][128 * 32];  // 2 x 8 KB
  const int tid  = threadIdx.x;
  const int wave = tid >> 6;
  const int lane = tid & 63;
  const int wm = wave >> 1, wn = wave & 1;
  int bm, bn;
  gemm_tile_map(bm, bn);
  const int quad = lane >> 4, r16 = lane & 15;

  floatx4 acc[4][4];
  #pragma unroll
  for (int i = 0; i < 4; ++i)
    #pragma unroll
    for (int j = 0; j < 4; ++j) acc[i][j] = {0.f, 0.f, 0.f, 0.f};

  // staging geometry (chunk = wave*2 + c, c in {0,1}; 512 elems = 1 KB each)
  const int ch0 = wave * 2;
  const int r0  = lane >> 2;        // 0..15 within chunk
  const int ce  = (lane & 3) * 8;   // col element 0,8,16,24
  const bf16_t* Ag0 = A + (size_t)(bm + ch0 * 16 + r0) * K + ce;
  const bf16_t* Ag1 = Ag0 + (size_t)16 * K;
  const bf16_t* Wg0 = W + (size_t)(bn + ch0 * 16 + r0) * K + ce;
  const bf16_t* Wg1 = Wg0 + (size_t)16 * K;

  auto stage = [&](int k0, int b) {
    g2l16(Ag0 + k0, &sA[b][ch0 * 512]);
    g2l16(Ag1 + k0, &sA[b][(ch0 + 1) * 512]);
    g2l16(Wg0 + k0, &sB[b][ch0 * 512]);
    g2l16(Wg1 + k0, &sB[b][(ch0 + 1) * 512]);
  };

  stage(0, 0);
  for (int t = 0; t < 32; ++t) {
    const int buf = t & 1;
    __syncthreads();                       // drains g2l(t): tiles resident
    if (t + 1 < 32) stage((t + 1) * 32, buf ^ 1);  // hides under compute(t)

    bf16x8 af[4], bv[4];
    #pragma unroll
    for (int mi = 0; mi < 4; ++mi)
      af[mi] = *(const bf16x8*)&sA[buf][(wm * 64 + mi * 16 + r16) * 32 + quad * 8];
    #pragma unroll
    for (int ni = 0; ni < 4; ++ni)
      bv[ni] = *(const bf16x8*)&sB[buf][(wn * 64 + ni * 16 + r16) * 32 + quad * 8];
    #pragma unroll
    for (int mi = 0; mi < 4; ++mi)
      #pragma unroll
      for (int ni = 0; ni < 4; ++ni)
        acc[mi][ni] = MFMA(af[mi], bv[ni], acc[mi][ni]);
  }

  #pragma unroll
  for (int mi = 0; mi < 4; ++mi)
    #pragma unroll
    for (int ni = 0; ni < 4; ++ni)
      #pragma unroll
      for (int r = 0; r < 4; ++r) {
        const int row = bm + wm * 64 + mi * 16 + quad * 4 + r;
        const int col = bn + wn * 64 + ni * 16 + r16;
        C[(size_t)row * 1024 + col] = (OutT)acc[mi][ni][r];
      }
}

// ---------------------------------------------------------------------------
// gemm_hyb: A bf16 via global_load_lds (linear [128][32]); W external f32 (or
// bf16 per flag) reg-staged + cvt into padded [128][40] LDS. Double-buffered,
// one barrier per k-step. Used for the K projection (no W-slot available).
// ---------------------------------------------------------------------------
template <bool WF32>
static __device__ __forceinline__
void gemm_hyb_core(const bf16_t* __restrict__ A, const void* __restrict__ Wv,
                   bf16_t* __restrict__ C,
                   bf16_t (*sA)[128 * 32], bf16_t (*sB)[128 * 40])
{
  const int K = 1024;
  const int tid  = threadIdx.x;
  const int wave = tid >> 6;
  const int lane = tid & 63;
  const int wm = wave >> 1, wn = wave & 1;
  int bm, bn;
  gemm_tile_map(bm, bn);
  const int quad = lane >> 4, r16 = lane & 15;

  floatx4 acc[4][4];
  #pragma unroll
  for (int i = 0; i < 4; ++i)
    #pragma unroll
    for (int j = 0; j < 4; ++j) acc[i][j] = {0.f, 0.f, 0.f, 0.f};

  const int ch0 = wave * 2;
  const int r0  = lane >> 2;
  const int ce  = (lane & 3) * 8;
  const bf16_t* Ag0 = A + (size_t)(bm + ch0 * 16 + r0) * K + ce;
  const bf16_t* Ag1 = Ag0 + (size_t)16 * K;

  const int srow = tid >> 2;
  const int scol = (tid & 3) * 8;
  const size_t w0 = (size_t)(bn + srow) * K + scol;
  const size_t w1 = w0 + (size_t)64 * K;

  floatx4 fw[2][2];
  bf16x8  bw[2];
  auto stageW = [&](int k0) {
    if constexpr (WF32) {
      const float* Wf = (const float*)Wv;
      fw[0][0] = *(const floatx4*)(Wf + w0 + k0);
      fw[0][1] = *(const floatx4*)(Wf + w0 + k0 + 4);
      fw[1][0] = *(const floatx4*)(Wf + w1 + k0);
      fw[1][1] = *(const floatx4*)(Wf + w1 + k0 + 4);
    } else {
      const bf16_t* Wb = (const bf16_t*)Wv;
      bw[0] = *(const bf16x8*)(Wb + w0 + k0);
      bw[1] = *(const bf16x8*)(Wb + w1 + k0);
    }
  };

  stageW(0);
  g2l16(Ag0, &sA[0][ch0 * 512]);
  g2l16(Ag1, &sA[0][(ch0 + 1) * 512]);

  for (int t = 0; t < 32; ++t) {
    const int buf = t & 1;
    {
      bf16x8 vb0, vb1;
      if constexpr (WF32) { vb0 = cvt8p(fw[0][0], fw[0][1]); vb1 = cvt8p(fw[1][0], fw[1][1]); }
      else                { vb0 = bw[0]; vb1 = bw[1]; }
      *(bf16x8*)&sB[buf][srow * 40 + scol]        = vb0;
      *(bf16x8*)&sB[buf][(srow + 64) * 40 + scol] = vb1;
    }
    __syncthreads();  // drains g2l A(t); W writes visible
    if (t + 1 < 32) {
      const int k0 = (t + 1) * 32;
      g2l16(Ag0 + k0, &sA[buf ^ 1][ch0 * 512]);
      g2l16(Ag1 + k0, &sA[buf ^ 1][(ch0 + 1) * 512]);
      stageW(k0);
    }

    bf16x8 af[4], bv[4];
    #pragma unroll
    for (int mi = 0; mi < 4; ++mi)
      af[mi] = *(const bf16x8*)&sA[buf][(wm * 64 + mi * 16 + r16) * 32 + quad * 8];
    #pragma unroll
    for (int ni = 0; ni < 4; ++ni)
      bv[ni] = *(const bf16x8*)&sB[buf][(wn * 64 + ni * 16 + r16) * 40 + quad * 8];
    #pragma unroll
    for (int mi = 0; mi < 4; ++mi)
      #pragma unroll
      for (int ni = 0; ni < 4; ++ni)
        acc[mi][ni] = MFMA(af[mi], bv[ni], acc[mi][ni]);
  }

  #pragma unroll
  for (int mi = 0; mi < 4; ++mi)
    #pragma unroll
    for (int ni = 0; ni < 4; ++ni)
      #pragma unroll
      for (int r = 0; r < 4; ++r) {
        const int row = bm + wm * 64 + mi * 16 + quad * 4 + r;
        const int col = bn + wn * 64 + ni * 16 + r16;
        C[(size_t)row * 1024 + col] = (bf16_t)acc[mi][ni][r];
      }
}

__global__ __launch_bounds__(256, 2)
void gemm_hyb(const bf16_t* __restrict__ A, const void* __restrict__ Wv,
              bf16_t* __restrict__ C, const int* __restrict__ flag)
{
  __shared__ __align__(16) bf16_t sA[2][128 * 32];  // 16 KB
  __shared__ __align__(16) bf16_t sB[2][128 * 40];  // 20 KB
  if (*flag) gemm_hyb_core<true >(A, Wv, C, sA, sB);
  else       gemm_hyb_core<false>(A, Wv, C, sA, sB);
}

// ---------------------------------------------------------------------------
// Causal MFMA flash attention over row-major [8192][1024] bf16 q/k/v, head =
// 64-col slice. Block = 256 threads (4 waves): one (bh, 64-row q-tile).
// Wave w owns q-rows [w*16, w*16+16). BKV = 64.
// R12: swapped QK^T — st = mfma(K_frag, Q_frag) gives, per lane, scores for
// ONE q-row (col=lane&15) at kv = nk*16 + quad*4 + r. Softmax is lane-local:
// 15 fmax + 2 shfl_xor (off 16,32) for max, same for sum; P packed as bf16x4
// (kv-consecutive) into swizzled sP; o-rescale alphas broadcast by 4 shfl
// only on tiles where a row-max grows (T13 skip). PV unchanged.
// XCD-grouped block map: all 32 q-tiles of one bh on one XCD (K/V L2-hot),
// heavy tiles first. LDS 24 KB swizzled (idx = row*64 + (col^((row&7)<<3))).
// K/V reg-prefetch after the stage barrier (T14).
// ---------------------------------------------------------------------------
__global__ __launch_bounds__(256, 4)
void flash_attn(bf16_t* qio, const bf16_t* __restrict__ kh,
                const bf16_t* __restrict__ vh)
{
  __shared__ __align__(16) bf16_t sK[64 * 64];    // [kv][d]  8 KB, swizzled
  __shared__ __align__(16) bf16_t sVt[64 * 64];   // [d][kv]  8 KB, swizzled
  __shared__ __align__(16) bf16_t sP[64 * 64];    // [q][kv]  8 KB, swizzled
  const int tid  = threadIdx.x;
  const int wave = tid >> 6;
  const int lane = tid & 63;
  const int quad = lane >> 4, r16 = lane & 15;

  // XCD-grouped mapping (nwg = 2048, %8==0 -> bijective): XCD j <- f%8 gets
  // 8 bh (j, j+8, ...), each as 32 consecutive q-tiles, heavy-first.
  const int f  = (int)(blockIdx.y * gridDim.x + blockIdx.x);
  const int xj = f & 7, sq = f >> 3;
  const int bh = xj + (sq >> 5) * 8;
  const int q0 = (31 - (sq & 31)) * 64;
  const int b = bh >> 4, h = bh & 15;
  const size_t hb = ((size_t)b * 2048) * 1024 + (size_t)h * 64;
  const int swl = (r16 & 7) << 3;  // swizzle XOR for r16-indexed rows

  // Q fragments (reused across all kv tiles): rows q0 + wave*16 + r16
  bf16x8 qf[2];
  #pragma unroll
  for (int ks = 0; ks < 2; ++ks)
    qf[ks] = *(const bf16x8*)(qio + hb +
        (size_t)(q0 + wave * 16 + r16) * 1024 + ks * 32 + quad * 8);

  floatx4 o[4];
  #pragma unroll
  for (int nd = 0; nd < 4; ++nd) o[nd] = {0.f, 0.f, 0.f, 0.f};
  float mrow = NEG_BIG, lrow = 0.f;  // state for q-row (wave*16 + r16)

  const float sc = 0.125f * 1.44269504089f;  // 1/sqrt(64) * log2(e)
  const int kend = q0 + 64;
  const int qrow = q0 + wave * 16 + r16;

  // staging decomposition (per thread, per j): K chunk (row c>>3, col (c&7)*8)
  // and V chunk (row c&63, col (c>>6)*8), c = j*256 + tid.
  bf16x8 kst[2], vst[2];
  #pragma unroll
  for (int j = 0; j < 2; ++j) {
    const int c = j * 256 + tid;
    kst[j] = *(const bf16x8*)(kh + hb + (size_t)(c >> 3) * 1024 + (c & 7) * 8);
    vst[j] = *(const bf16x8*)(vh + hb + (size_t)(c & 63) * 1024 + (c >> 6) * 8);
  }

  for (int kv0 = 0; kv0 < kend; kv0 += 64) {
    // ---- write staged regs -> LDS (swizzled) ----
    #pragma unroll
    for (int j = 0; j < 2; ++j) {
      const int c = j * 256 + tid;
      const int krow = c >> 3, kcol = (c & 7) * 8;
      *(bf16x8*)&sK[krow * 64 + (kcol ^ ((krow & 7) << 3))] = kst[j];
      const int vkv = c & 63, vd = (c >> 6) * 8;
      #pragma unroll
      for (int e = 0; e < 8; ++e)        // row = vd+e, (row&7)==e since vd%8==0
        sVt[(vd + e) * 64 + (vkv ^ (e << 3))] = vst[j][e];
    }
    __syncthreads();

    // ---- prefetch next tile into regs; latency hides under QK/softmax/PV ----
    if (kv0 + 64 < kend) {
      #pragma unroll
      for (int j = 0; j < 2; ++j) {
        const int c = j * 256 + tid;
        kst[j] = *(const bf16x8*)(kh + hb + (size_t)(kv0 + 64 + (c >> 3)) * 1024 + (c & 7) * 8);
        vst[j] = *(const bf16x8*)(vh + hb + (size_t)(kv0 + 64 + (c & 63)) * 1024 + (c >> 6) * 8);
      }
    }

    // ---- S^T = K Q^T (swapped operands; lane owns q-row r16) ----
    floatx4 st[4];
    #pragma unroll
    for (int nk = 0; nk < 4; ++nk) st[nk] = {0.f, 0.f, 0.f, 0.f};
    #pragma unroll
    for (int ks = 0; ks < 2; ++ks) {
      bf16x8 bk[4];
      #pragma unroll
      for (int nk = 0; nk < 4; ++nk)
        bk[nk] = *(const bf16x8*)&sK[(nk * 16 + r16) * 64 + ((ks * 32 + quad * 8) ^ swl)];
      #pragma unroll
      for (int nk = 0; nk < 4; ++nk)
        st[nk] = MFMA(bk[nk], qf[ks], st[nk]);  // args swapped vs QK
    }

    // ---- scale + causal mask (kv = kv0 + nk*16 + quad*4 + r vs qrow) ----
    const bool domask = (kv0 + 63 > q0 + wave * 16);  // wave-uniform
    #pragma unroll
    for (int nk = 0; nk < 4; ++nk)
      #pragma unroll
      for (int r = 0; r < 4; ++r) {
        float t = st[nk][r] * sc;
        if (domask && (kv0 + nk * 16 + quad * 4 + r > qrow)) t = NEG_BIG;
        st[nk][r] = t;
      }

    // ---- lane-local softmax ----
    float mx = fmaxf(fmaxf(st[0][0], st[0][1]), fmaxf(st[0][2], st[0][3]));
    #pragma unroll
    for (int nk = 1; nk < 4; ++nk)
      mx = fmaxf(mx, fmaxf(fmaxf(st[nk][0], st[nk][1]),
                           fmaxf(st[nk][2], st[nk][3])));
    mx = fmaxf(mx, __shfl_xor(mx, 16, 64));
    mx = fmaxf(mx, __shfl_xor(mx, 32, 64));

    if (!__all(mx <= mrow)) {            // T13: skip rescale if no max grew
      const float mnew  = fmaxf(mrow, mx);
      const float alpha = exp2f(mrow - mnew);
      mrow = mnew;
      lrow *= alpha;
      #pragma unroll
      for (int r = 0; r < 4; ++r) {      // alpha for o-rows q = quad*4 + r
        const float ar = __shfl(alpha, quad * 4 + r, 64);
        #pragma unroll
        for (int nd = 0; nd < 4; ++nd) o[nd][r] *= ar;
      }
    }

    // ---- P = exp2(S - m), packed bf16x4 (kv-consecutive) -> swizzled sP ----
    float ls = 0.f;
    #pragma unroll
    for (int nk = 0; nk < 4; ++nk) {
      bf16x4 pk;
      #pragma unroll
      for (int r = 0; r < 4; ++r) {
        const bf16_t pb = f2bf(exp2f(st[nk][r] - mrow));
        ls += (float)pb;  // denominator matches the bf16 P used in PV
        pk[r] = pb;
      }
      *(bf16x4*)&sP[(wave * 16 + r16) * 64 + ((nk * 16 + quad * 4) ^ swl)] = pk;
    }
    ls += __shfl_xor(ls, 16, 64);
    ls += __shfl_xor(ls, 32, 64);
    lrow += ls;
    __syncthreads();  // sP visible across lanes

    // ---- O += P V ----
    #pragma unroll
    for (int ks = 0; ks < 2; ++ks) {
      const int cb = (ks * 32 + quad * 8) ^ swl;
      const bf16x8 pa = *(const bf16x8*)&sP[(wave * 16 + r16) * 64 + cb];
      bf16x8 vb[4];
      #pragma unroll
      for (int nd = 0; nd < 4; ++nd)
        vb[nd] = *(const bf16x8*)&sVt[(nd * 16 + r16) * 64 + cb];
      #pragma unroll
      for (int nd = 0; nd < 4; ++nd)
        o[nd] = MFMA(pa, vb[nd], o[nd]);
    }
    __syncthreads();  // protect sK/sVt/sP for next iteration
  }

  // ---- normalize + store (l broadcast from softmax-layout lanes) ----
  #pragma unroll
  for (int r = 0; r < 4; ++r) {
    const float lr  = __shfl(lrow, quad * 4 + r, 64);
    const float inv = 1.f / lr;
    const int row = q0 + wave * 16 + quad * 4 + r;
    #pragma unroll
    for (int nd = 0; nd < 4; ++nd)
      qio[hb + (size_t)row * 1024 + nd * 16 + r16] = f2bf(o[nd][r] * inv);
  }
}

// ---------------------------------------------------------------------------
extern "C" void kernel_launch(void* const* d_in, const int* in_sizes, int n_in,
                              void* d_out, int out_size, void* d_ws, size_t ws_size,
                              hipStream_t stream) {
  (void)in_sizes; (void)n_in; (void)out_size; (void)ws_size;
  const size_t TSZ = (size_t)8192 * 1024;       // elems per [8192,1024] bf16
  const size_t WSZ = (size_t)1024 * 1024;       // elems per [1024,1024] bf16
  int*    flag = (int*)d_ws;
  bf16_t* qws  = (bf16_t*)((char*)d_ws + 16);   // ws lo  16 MB
  bf16_t* kws  = qws + TSZ;                     // ws hi  16 MB (also W-slot)
  bf16_t* vws  = (bf16_t*)d_out;                // d_out lo 16 MB (bf16 V)
  bf16_t* abuf = (bf16_t*)d_out + TSZ;          // d_out hi 16 MB (converted A)

  const int nA8 = (int)(TSZ / 8);
  const int nW8 = (int)(WSZ / 8);

  detect_dtype<<<1, 64, 0, stream>>>((const unsigned short*)d_in[3], flag);

  const dim3 gg(8, 64);  // (N/128, M/128)

  // V first: kws region free -> holds converted w_v
  cvt_bf16<<<nA8 / 256, 256, 0, stream>>>(d_in[2], abuf, nA8, flag);
  cvt_bf16<<<nW8 / 256, 256, 0, stream>>>(d_in[5], kws, nW8, flag);
  gemm_lds2<bf16_t><<<gg, 256, 0, stream>>>(abuf, kws, vws);

  // Q second: kws region still free -> holds converted w_q
  cvt_bf16<<<nA8 / 256, 256, 0, stream>>>(d_in[0], abuf, nA8, flag);
  cvt_bf16<<<nW8 / 256, 256, 0, stream>>>(d_in[3], kws, nW8, flag);
  gemm_lds2<bf16_t><<<gg, 256, 0, stream>>>(abuf, kws, qws);

  // K third: no free region -> hybrid (W f32 reg-staged from d_in)
  cvt_bf16<<<nA8 / 256, 256, 0, stream>>>(d_in[1], abuf, nA8, flag);
  gemm_hyb<<<gg, 256, 0, stream>>>(abuf, d_in[4], kws, flag);

  flash_attn<<<dim3(64, 32), 256, 0, stream>>>(qws, kws, vws);

  // Output projection: K dead -> kws region holds converted w_o
  cvt_bf16<<<nW8 / 256, 256, 0, stream>>>(d_in[6], kws, nW8, flag);
  gemm_lds2<float><<<gg, 256, 0, stream>>>(qws, kws, (float*)d_out);
}

// Round 7
// 402.260 us; speedup vs baseline: 1.2663x; 1.0445x over previous
//
#include <hip/hip_runtime.h>
#include <hip/hip_bf16.h>
#include <cstdint>
#include <cstddef>

// MHA forward. b=4, n=2048, d_model=1024, heads=16, dk=64, causal.
// Inputs: float32 (confirmed R1-R5). Output: float32 (confirmed R5 green).
// Compute: bf16 MFMA, fp32 accumulate; intermediates bf16 row-major [b*n,1024].
//
// R13: GEMM phase (~275 us) was grid-starved: 512 blocks = 2 blocks/CU =
// 2 waves/SIMD; per-step critical path = barrier + unhidden L2 latency +
// 8-way-conflicted ds_reads on the linear [128][32] g2l tile (stride-64B rows
// -> 16 lanes collide 8-way).
//   - Q/K/V projections merged into ONE dispatch, grid (8,64,3): 1536 blocks,
//     3 blocks/CU (launch_bounds(256,3), LDS 36 KB). A reg-staged f32 straight
//     from d_in (A-cvt passes deleted); W bf16 via global_load_lds.
//   - W LDS conflict fix (rule 21): cvt pre-pass stores W swizzled
//     (dst[r][c ^ ((r&6)<<2)], involution, 8-aligned-preserving); g2l dest
//     stays linear; bv read XORs the same mask (per-lane constant cW, hoisted).
//     A side uses validated padded [128][40] (2-way = free).
//   - Output proj = same kernel, ADT=1 (A = qws bf16), grid (8,64,1).
// Launches 13 -> 6. Same RNE casts everywhere -> results bit-identical.
// flash_attn unchanged (R12: swapped-QK softmax + XCD grouping, 143 us).

typedef __bf16 bf16_t;
typedef bf16_t bf16x4 __attribute__((ext_vector_type(4)));
typedef bf16_t bf16x8 __attribute__((ext_vector_type(8)));
typedef float floatx4 __attribute__((ext_vector_type(4)));

#define MFMA(a, b, c) __builtin_amdgcn_mfma_f32_16x16x32_bf16((a), (b), (c), 0, 0, 0)
#define NEG_BIG (-30000.0f)  // exp2-domain sentinel; v_exp_f32 underflows to 0

static __device__ __forceinline__ bf16_t f2bf(float x) { return (bf16_t)x; }

static __device__ __forceinline__ bf16x8 cvt8p(const floatx4 a, const floatx4 b) {
  bf16x8 r;
  r[0] = (bf16_t)a[0]; r[1] = (bf16_t)a[1]; r[2] = (bf16_t)a[2]; r[3] = (bf16_t)a[3];
  r[4] = (bf16_t)b[0]; r[5] = (bf16_t)b[1]; r[6] = (bf16_t)b[2]; r[7] = (bf16_t)b[3];
  return r;
}

// global -> LDS direct copy, 16 B/lane. dest = wave-uniform base + lane*16.
static __device__ __forceinline__ void g2l16(const void* g, void* l) {
  __builtin_amdgcn_global_load_lds(
      (const __attribute__((address_space(1))) void*)g,
      (__attribute__((address_space(3))) void*)l, 16, 0, 0);
}

// f32-vs-bf16 sniffer on w_q's first 64 uint16s (validated: picks f32 path).
__global__ void detect_dtype(const unsigned short* __restrict__ w,
                             int* __restrict__ flag) {
  const unsigned short u = w[threadIdx.x];
  const bool big = (u & 0x7F80u) >= 0x3F80u;
  const unsigned long long m = __ballot(big);
  if (threadIdx.x == 0) *flag = (m != 0ull) ? 1 : 0;
}

// ---------------------------------------------------------------------------
// W cvt + bank-swizzle: dst[r][c] = src[r][c ^ ((r&6)<<2)] (flips col bits 3,4
// within each 32-col block; involution; preserves 8-elem alignment).
// grid (512, nmat); blockIdx.y picks src; dst slots are WSZ apart.
// ---------------------------------------------------------------------------
__global__ __launch_bounds__(256)
void cvt_w_swz(const void* __restrict__ s0, const void* __restrict__ s1,
               const void* __restrict__ s2, bf16_t* __restrict__ dst,
               const int* __restrict__ flag)
{
  const void* src = blockIdx.y == 0 ? s0 : (blockIdx.y == 1 ? s1 : s2);
  bf16_t* d = dst + (size_t)blockIdx.y * (1024 * 1024);
  const int i    = blockIdx.x * 256 + threadIdx.x;  // 0..131071
  const int row  = i >> 7;
  const int col0 = (i & 127) * 8;
  const int dcol = col0 ^ ((row & 6) << 2);
  bf16x8 v;
  if (*flag) {
    const float* s = (const float*)src + (size_t)row * 1024 + col0;
    v = cvt8p(*(const floatx4*)s, *(const floatx4*)(s + 4));
  } else {
    v = *(const bf16x8*)((const bf16_t*)src + (size_t)row * 1024 + col0);
  }
  *(bf16x8*)(d + (size_t)row * 1024 + dcol) = v;
}

// XCD remap for each 8x64 GEMM slab (512 blocks, %8==0 -> bijective):
// XCD j <- f%8 owns bm-panels [j*8, j*8+8) x all 8 bn. A/W panels L2-hot.
static __device__ __forceinline__ void gemm_tile_map(int& bm, int& bn) {
  const int f  = (int)(blockIdx.y * gridDim.x + blockIdx.x);
  const int xj = f & 7, sq = f >> 3;
  bm = ((xj << 3) | (sq >> 3)) * 128;
  bn = (sq & 7) * 128;
}

// ---------------------------------------------------------------------------
// gemm_rs: C[M,1024] = A[M,1024] @ W[1024,1024]^T.
// A reg-staged (f32->cvt or bf16 passthrough) -> padded [128][40] LDS (2-way,
// free). W bf16 pre-swizzled in global -> linear [128][32] via g2l; bv read
// applies cW = quad*8 ^ ((r16&6)<<2) -> conflict-free (2-way).
// Tile 128x128, BK=32, 4 waves (2x2), double-buffered, ONE barrier/k-step:
// sync(t) drains W g2l(t) (issued after sync(t-1), hidden under compute(t-1));
// A(t) regs loaded after sync(t-1), written to LDS at top of t, before sync(t).
// ---------------------------------------------------------------------------
template <bool AF32, typename OutT>
static __device__ __forceinline__
void gemm_rs_core(const void* __restrict__ Av, const bf16_t* __restrict__ W,
                  OutT* __restrict__ C,
                  bf16_t (*sA)[128 * 40], bf16_t (*sB)[128 * 32])
{
  const int K = 1024;
  const int tid  = threadIdx.x;
  const int wave = tid >> 6;
  const int lane = tid & 63;
  const int wm = wave >> 1, wn = wave & 1;
  int bm, bn;
  gemm_tile_map(bm, bn);
  const int quad = lane >> 4, r16 = lane & 15;
  const int cW = (quad * 8) ^ ((r16 & 6) << 2);  // swizzled W read col

  floatx4 acc[4][4];
  #pragma unroll
  for (int i = 0; i < 4; ++i)
    #pragma unroll
    for (int j = 0; j < 4; ++j) acc[i][j] = {0.f, 0.f, 0.f, 0.f};

  // A reg-stage geometry (rows bm+srow, bm+srow+64; 8 elems each)
  const int srow = tid >> 2;
  const int scol = (tid & 3) * 8;
  const size_t a0 = (size_t)(bm + srow) * K + scol;
  const size_t a1 = a0 + (size_t)64 * K;

  // W g2l geometry (chunk = wave*2 + c; 16 rows x 32 cols = 1 KB each)
  const int ch0 = wave * 2;
  const int r0  = lane >> 2;
  const int ce  = (lane & 3) * 8;
  const bf16_t* Wg0 = W + (size_t)(bn + ch0 * 16 + r0) * K + ce;
  const bf16_t* Wg1 = Wg0 + (size_t)16 * K;

  floatx4 fa[2][2];
  bf16x8  ba[2];
  auto stageA = [&](int k0) {
    if constexpr (AF32) {
      const float* Af = (const float*)Av;
      fa[0][0] = *(const floatx4*)(Af + a0 + k0);
      fa[0][1] = *(const floatx4*)(Af + a0 + k0 + 4);
      fa[1][0] = *(const floatx4*)(Af + a1 + k0);
      fa[1][1] = *(const floatx4*)(Af + a1 + k0 + 4);
    } else {
      const bf16_t* Ab = (const bf16_t*)Av;
      ba[0] = *(const bf16x8*)(Ab + a0 + k0);
      ba[1] = *(const bf16x8*)(Ab + a1 + k0);
    }
  };

  stageA(0);
  g2l16(Wg0, &sB[0][ch0 * 512]);
  g2l16(Wg1, &sB[0][(ch0 + 1) * 512]);

  for (int t = 0; t < 32; ++t) {
    const int buf = t & 1;
    {  // A(t) regs -> LDS (WAR-safe: last reader passed sync(t-1))
      bf16x8 va0, va1;
      if constexpr (AF32) { va0 = cvt8p(fa[0][0], fa[0][1]); va1 = cvt8p(fa[1][0], fa[1][1]); }
      else                { va0 = ba[0]; va1 = ba[1]; }
      *(bf16x8*)&sA[buf][srow * 40 + scol]        = va0;
      *(bf16x8*)&sA[buf][(srow + 64) * 40 + scol] = va1;
    }
    __syncthreads();  // drains W g2l(t); A writes visible
    if (t + 1 < 32) {
      const int k0 = (t + 1) * 32;
      g2l16(Wg0 + k0, &sB[buf ^ 1][ch0 * 512]);
      g2l16(Wg1 + k0, &sB[buf ^ 1][(ch0 + 1) * 512]);
      stageA(k0);
    }

    bf16x8 af[4], bv[4];
    #pragma unroll
    for (int mi = 0; mi < 4; ++mi)
      af[mi] = *(const bf16x8*)&sA[buf][(wm * 64 + mi * 16 + r16) * 40 + quad * 8];
    #pragma unroll
    for (int ni = 0; ni < 4; ++ni)
      bv[ni] = *(const bf16x8*)&sB[buf][(wn * 64 + ni * 16 + r16) * 32 + cW];
    #pragma unroll
    for (int mi = 0; mi < 4; ++mi)
      #pragma unroll
      for (int ni = 0; ni < 4; ++ni)
        acc[mi][ni] = MFMA(af[mi], bv[ni], acc[mi][ni]);
  }

  #pragma unroll
  for (int mi = 0; mi < 4; ++mi)
    #pragma unroll
    for (int ni = 0; ni < 4; ++ni)
      #pragma unroll
      for (int r = 0; r < 4; ++r) {
        const int row = bm + wm * 64 + mi * 16 + quad * 4 + r;
        const int col = bn + wn * 64 + ni * 16 + r16;
        C[(size_t)row * 1024 + col] = (OutT)acc[mi][ni][r];
      }
}

// ADT 0: A external (f32/bf16 per flag), z in {0,1,2} picks A/W/C.
// ADT 1: A internal bf16 (grid z=1).
template <int ADT, typename OutT>
__global__ __launch_bounds__(256, 3)
void gemm_rs(const void* __restrict__ A0, const void* __restrict__ A1,
             const void* __restrict__ A2, const bf16_t* __restrict__ Wb,
             OutT* __restrict__ C0, OutT* __restrict__ C1,
             OutT* __restrict__ C2, const int* __restrict__ flag)
{
  __shared__ __align__(16) bf16_t sA[2][128 * 40];  // 20 KB
  __shared__ __align__(16) bf16_t sB[2][128 * 32];  // 16 KB
  const int z = blockIdx.z;
  const void*   A = z == 0 ? A0 : (z == 1 ? A1 : A2);
  const bf16_t* W = Wb + (size_t)z * (1024 * 1024);
  OutT*         C = z == 0 ? C0 : (z == 1 ? C1 : C2);
  if (ADT == 0 && *flag) gemm_rs_core<true,  OutT>(A, W, C, sA, sB);
  else                   gemm_rs_core<false, OutT>(A, W, C, sA, sB);
}

// ---------------------------------------------------------------------------
// Causal MFMA flash attention over row-major [8192][1024] bf16 q/k/v, head =
// 64-col slice. Block = 256 threads (4 waves): one (bh, 64-row q-tile).
// Wave w owns q-rows [w*16, w*16+16). BKV = 64. Swapped QK^T: lane owns one
// q-row -> lane-local softmax (15 fmax + 2 shfl), T13 skip-rescale, bf16x4 P
// stores. XCD-grouped block map (K/V L2-hot), heavy tiles first. LDS 24 KB
// swizzled (idx = row*64 + (col^((row&7)<<3))). K/V reg-prefetch (T14).
// [R6: 143 us; unchanged this round]
// ---------------------------------------------------------------------------
__global__ __launch_bounds__(256, 4)
void flash_attn(bf16_t* qio, const bf16_t* __restrict__ kh,
                const bf16_t* __restrict__ vh)
{
  __shared__ __align__(16) bf16_t sK[64 * 64];    // [kv][d]  8 KB, swizzled
  __shared__ __align__(16) bf16_t sVt[64 * 64];   // [d][kv]  8 KB, swizzled
  __shared__ __align__(16) bf16_t sP[64 * 64];    // [q][kv]  8 KB, swizzled
  const int tid  = threadIdx.x;
  const int wave = tid >> 6;
  const int lane = tid & 63;
  const int quad = lane >> 4, r16 = lane & 15;

  const int f  = (int)(blockIdx.y * gridDim.x + blockIdx.x);
  const int xj = f & 7, sq = f >> 3;
  const int bh = xj + (sq >> 5) * 8;
  const int q0 = (31 - (sq & 31)) * 64;
  const int b = bh >> 4, h = bh & 15;
  const size_t hb = ((size_t)b * 2048) * 1024 + (size_t)h * 64;
  const int swl = (r16 & 7) << 3;  // swizzle XOR for r16-indexed rows

  bf16x8 qf[2];
  #pragma unroll
  for (int ks = 0; ks < 2; ++ks)
    qf[ks] = *(const bf16x8*)(qio + hb +
        (size_t)(q0 + wave * 16 + r16) * 1024 + ks * 32 + quad * 8);

  floatx4 o[4];
  #pragma unroll
  for (int nd = 0; nd < 4; ++nd) o[nd] = {0.f, 0.f, 0.f, 0.f};
  float mrow = NEG_BIG, lrow = 0.f;  // state for q-row (wave*16 + r16)

  const float sc = 0.125f * 1.44269504089f;  // 1/sqrt(64) * log2(e)
  const int kend = q0 + 64;
  const int qrow = q0 + wave * 16 + r16;

  bf16x8 kst[2], vst[2];
  #pragma unroll
  for (int j = 0; j < 2; ++j) {
    const int c = j * 256 + tid;
    kst[j] = *(const bf16x8*)(kh + hb + (size_t)(c >> 3) * 1024 + (c & 7) * 8);
    vst[j] = *(const bf16x8*)(vh + hb + (size_t)(c & 63) * 1024 + (c >> 6) * 8);
  }

  for (int kv0 = 0; kv0 < kend; kv0 += 64) {
    #pragma unroll
    for (int j = 0; j < 2; ++j) {
      const int c = j * 256 + tid;
      const int krow = c >> 3, kcol = (c & 7) * 8;
      *(bf16x8*)&sK[krow * 64 + (kcol ^ ((krow & 7) << 3))] = kst[j];
      const int vkv = c & 63, vd = (c >> 6) * 8;
      #pragma unroll
      for (int e = 0; e < 8; ++e)        // row = vd+e, (row&7)==e since vd%8==0
        sVt[(vd + e) * 64 + (vkv ^ (e << 3))] = vst[j][e];
    }
    __syncthreads();

    if (kv0 + 64 < kend) {
      #pragma unroll
      for (int j = 0; j < 2; ++j) {
        const int c = j * 256 + tid;
        kst[j] = *(const bf16x8*)(kh + hb + (size_t)(kv0 + 64 + (c >> 3)) * 1024 + (c & 7) * 8);
        vst[j] = *(const bf16x8*)(vh + hb + (size_t)(kv0 + 64 + (c & 63)) * 1024 + (c >> 6) * 8);
      }
    }

    floatx4 st[4];
    #pragma unroll
    for (int nk = 0; nk < 4; ++nk) st[nk] = {0.f, 0.f, 0.f, 0.f};
    #pragma unroll
    for (int ks = 0; ks < 2; ++ks) {
      bf16x8 bk[4];
      #pragma unroll
      for (int nk = 0; nk < 4; ++nk)
        bk[nk] = *(const bf16x8*)&sK[(nk * 16 + r16) * 64 + ((ks * 32 + quad * 8) ^ swl)];
      #pragma unroll
      for (int nk = 0; nk < 4; ++nk)
        st[nk] = MFMA(bk[nk], qf[ks], st[nk]);  // swapped operands
    }

    const bool domask = (kv0 + 63 > q0 + wave * 16);  // wave-uniform
    #pragma unroll
    for (int nk = 0; nk < 4; ++nk)
      #pragma unroll
      for (int r = 0; r < 4; ++r) {
        float t = st[nk][r] * sc;
        if (domask && (kv0 + nk * 16 + quad * 4 + r > qrow)) t = NEG_BIG;
        st[nk][r] = t;
      }

    float mx = fmaxf(fmaxf(st[0][0], st[0][1]), fmaxf(st[0][2], st[0][3]));
    #pragma unroll
    for (int nk = 1; nk < 4; ++nk)
      mx = fmaxf(mx, fmaxf(fmaxf(st[nk][0], st[nk][1]),
                           fmaxf(st[nk][2], st[nk][3])));
    mx = fmaxf(mx, __shfl_xor(mx, 16, 64));
    mx = fmaxf(mx, __shfl_xor(mx, 32, 64));

    if (!__all(mx <= mrow)) {            // T13: skip rescale if no max grew
      const float mnew  = fmaxf(mrow, mx);
      const float alpha = exp2f(mrow - mnew);
      mrow = mnew;
      lrow *= alpha;
      #pragma unroll
      for (int r = 0; r < 4; ++r) {
        const float ar = __shfl(alpha, quad * 4 + r, 64);
        #pragma unroll
        for (int nd = 0; nd < 4; ++nd) o[nd][r] *= ar;
      }
    }

    float ls = 0.f;
    #pragma unroll
    for (int nk = 0; nk < 4; ++nk) {
      bf16x4 pk;
      #pragma unroll
      for (int r = 0; r < 4; ++r) {
        const bf16_t pb = f2bf(exp2f(st[nk][r] - mrow));
        ls += (float)pb;  // denominator matches the bf16 P used in PV
        pk[r] = pb;
      }
      *(bf16x4*)&sP[(wave * 16 + r16) * 64 + ((nk * 16 + quad * 4) ^ swl)] = pk;
    }
    ls += __shfl_xor(ls, 16, 64);
    ls += __shfl_xor(ls, 32, 64);
    lrow += ls;
    __syncthreads();  // sP visible across lanes

    #pragma unroll
    for (int ks = 0; ks < 2; ++ks) {
      const int cb = (ks * 32 + quad * 8) ^ swl;
      const bf16x8 pa = *(const bf16x8*)&sP[(wave * 16 + r16) * 64 + cb];
      bf16x8 vb[4];
      #pragma unroll
      for (int nd = 0; nd < 4; ++nd)
        vb[nd] = *(const bf16x8*)&sVt[(nd * 16 + r16) * 64 + cb];
      #pragma unroll
      for (int nd = 0; nd < 4; ++nd)
        o[nd] = MFMA(pa, vb[nd], o[nd]);
    }
    __syncthreads();  // protect sK/sVt/sP for next iteration
  }

  #pragma unroll
  for (int r = 0; r < 4; ++r) {
    const float lr  = __shfl(lrow, quad * 4 + r, 64);
    const float inv = 1.f / lr;
    const int row = q0 + wave * 16 + quad * 4 + r;
    #pragma unroll
    for (int nd = 0; nd < 4; ++nd)
      qio[hb + (size_t)row * 1024 + nd * 16 + r16] = f2bf(o[nd][r] * inv);
  }
}

// ---------------------------------------------------------------------------
extern "C" void kernel_launch(void* const* d_in, const int* in_sizes, int n_in,
                              void* d_out, int out_size, void* d_ws, size_t ws_size,
                              hipStream_t stream) {
  (void)in_sizes; (void)n_in; (void)out_size; (void)ws_size;
  const size_t TSZ = (size_t)8192 * 1024;       // elems per [8192,1024] bf16
  int*    flag = (int*)d_ws;
  bf16_t* qws  = (bf16_t*)((char*)d_ws + 16);   // ws lo  16 MB
  bf16_t* kws  = qws + TSZ;                     // ws hi  16 MB (W_o slot later)
  bf16_t* vws  = (bf16_t*)d_out;                // d_out lo 16 MB (bf16 V)
  bf16_t* wsl  = (bf16_t*)d_out + TSZ;          // d_out hi: 3 x 2 MB W slots

  detect_dtype<<<1, 64, 0, stream>>>((const unsigned short*)d_in[3], flag);

  // convert+swizzle w_q, w_k, w_v into the three slots
  cvt_w_swz<<<dim3(512, 3), 256, 0, stream>>>(d_in[3], d_in[4], d_in[5], wsl, flag);

  // fused Q/K/V projections: one dispatch, 1536 blocks (3 blocks/CU)
  gemm_rs<0, bf16_t><<<dim3(8, 64, 3), 256, 0, stream>>>(
      d_in[0], d_in[1], d_in[2], wsl, qws, kws, vws, flag);

  flash_attn<<<dim3(64, 32), 256, 0, stream>>>(qws, kws, vws);

  // K dead -> its ws region holds converted+swizzled w_o
  cvt_w_swz<<<dim3(512, 1), 256, 0, stream>>>(d_in[6], d_in[6], d_in[6], kws, flag);

  // output projection: A = qws (bf16, internal), C = f32 d_out (full 32 MB)
  gemm_rs<1, float><<<dim3(8, 64, 1), 256, 0, stream>>>(
      qws, qws, qws, kws, (float*)d_out, (float*)d_out, (float*)d_out, flag);
}